// Round 9
// baseline (493.361 us; speedup 1.0000x reference)
//
#include <hip/hip_runtime.h>
#include <cstddef>

// Problem constants (fixed by the reference setup)
constexpr int NN = 100000;          // nodes
constexpr int NE = 1600000;         // edges (without self loops)
constexpr int TE = NE + NN;         // edges + self loops = 1,700,000
constexpr int NG = 64;              // graphs
constexpr float EPS = 1e-5f;
constexpr float NEG_SLOPE = 0.2f;
constexpr int NREP = 16;            // BN partial-sum replicas

// CSR bucket sort parameters
constexpr int NBUCK = 256;          // dst buckets
constexpr int DPB = 391;            // dsts per bucket (256*391 >= NN)
constexpr int PHB = 256;            // edge-chunk blocks
constexpr int CH = (TE + PHB - 1) / PHB;   // edges per chunk

// bf16 helpers (RNE pack, exact unpack)
__device__ __forceinline__ unsigned short f2bf(float f) {
    unsigned u = __float_as_uint(f);
    u += 0x7fffu + ((u >> 16) & 1u);
    return (unsigned short)(u >> 16);
}
__device__ __forceinline__ float bf2f(unsigned short s) {
    return __uint_as_float((unsigned)s << 16);
}
__device__ __forceinline__ float bflo(unsigned u) { return __uint_as_float(u << 16); }
__device__ __forceinline__ float bfhi(unsigned u) { return __uint_as_float(u & 0xffff0000u); }

// ---------------- CSR build: bucketed counting sort ----------------

__global__ void k_hist(const int* __restrict__ ei, int* __restrict__ hist) {
    __shared__ int hcnt[NBUCK];
    for (int i = threadIdx.x; i < NBUCK; i += 256) hcnt[i] = 0;
    __syncthreads();
    int k = blockIdx.x;
    int e0 = k * CH, e1 = min(e0 + CH, TE);
    for (int e = e0 + threadIdx.x; e < e1; e += 256) {
        int d = (e < NE) ? ei[NE + e] : (e - NE);
        atomicAdd(&hcnt[d / DPB], 1);
    }
    __syncthreads();
    for (int b = threadIdx.x; b < NBUCK; b += 256) hist[b * PHB + k] = hcnt[b];
}

__global__ void k_scanA(int* __restrict__ hist, int* __restrict__ bsum) {
    __shared__ int ls[PHB];
    int b = blockIdx.x, t = threadIdx.x;
    int v = hist[b * PHB + t];
    ls[t] = v;
    __syncthreads();
    for (int off = 1; off < PHB; off <<= 1) {
        int add = (t >= off) ? ls[t - off] : 0;
        __syncthreads();
        ls[t] += add;
        __syncthreads();
    }
    hist[b * PHB + t] = ls[t] - v;      // exclusive
    if (t == PHB - 1) bsum[b] = ls[t];  // bucket total
}

__global__ void k_scanB(const int* __restrict__ bsum, int* __restrict__ bbase,
                        int* __restrict__ rowptr) {
    __shared__ int ls[NBUCK];
    int t = threadIdx.x;
    int v = bsum[t];
    ls[t] = v;
    __syncthreads();
    for (int off = 1; off < NBUCK; off <<= 1) {
        int add = (t >= off) ? ls[t - off] : 0;
        __syncthreads();
        ls[t] += add;
        __syncthreads();
    }
    bbase[t] = ls[t] - v;
    if (t == NBUCK - 1) { bbase[NBUCK] = ls[t]; rowptr[NN] = ls[t]; }  // == TE
}

__global__ void k_scatter(const int* __restrict__ ei, const int* __restrict__ hist,
                          const int* __restrict__ bbase, int* __restrict__ pairs) {
    __shared__ int cur[NBUCK];
    int k = blockIdx.x;
    for (int b = threadIdx.x; b < NBUCK; b += 256) cur[b] = bbase[b] + hist[b * PHB + k];
    __syncthreads();
    int e0 = k * CH, e1 = min(e0 + CH, TE);
    for (int e = e0 + threadIdx.x; e < e1; e += 256) {
        int s, d;
        if (e < NE) { s = ei[e]; d = ei[NE + e]; } else { s = e - NE; d = s; }
        int b = d / DPB, ld = d - b * DPB;
        int pos = atomicAdd(&cur[b], 1);
        pairs[pos] = (s << 9) | ld;
    }
}

__global__ void k_csr(const int* __restrict__ pairs, const int* __restrict__ bbase,
                      int* __restrict__ rowptr, int* __restrict__ colsrc) {
    __shared__ int deg[DPB];     // counts, then reused as cursors
    __shared__ int exc[DPB];     // exclusive scan
    __shared__ int sc[512];
    int b = blockIdx.x, t = threadIdx.x;
    int base = bbase[b], cnt = bbase[b + 1] - base;
    int d0 = b * DPB;
    int ndst = min(DPB, NN - d0);
    for (int i = t; i < DPB; i += 256) deg[i] = 0;
    __syncthreads();
    for (int i = t; i < cnt; i += 256) atomicAdd(&deg[pairs[base + i] & 511], 1);
    __syncthreads();
    sc[t] = (t < DPB) ? deg[t] : 0;
    sc[t + 256] = (t + 256 < DPB) ? deg[t + 256] : 0;
    __syncthreads();
    for (int off = 1; off < 512; off <<= 1) {
        int a0 = (t >= off) ? sc[t - off] : 0;
        int a1 = (t + 256 >= off) ? sc[t + 256 - off] : 0;
        __syncthreads();
        sc[t] += a0; sc[t + 256] += a1;
        __syncthreads();
    }
    if (t < DPB) exc[t] = sc[t] - deg[t];
    if (t + 256 < DPB) exc[t + 256] = sc[t + 256] - deg[t + 256];
    __syncthreads();
    for (int i = t; i < ndst; i += 256) rowptr[d0 + i] = base + exc[i];
    for (int i = t; i < DPB; i += 256) deg[i] = 0;   // reuse as cursor
    __syncthreads();
    for (int i = t; i < cnt; i += 256) {
        int p = pairs[base + i];
        int ld = p & 511;
        int s = (unsigned)p >> 9;
        int pos = base + exc[ld] + atomicAdd(&deg[ld], 1);
        colsrc[pos] = s;
    }
}

// ---------------- Node transform ----------------
// Input (BN layers): bf16 SLICE-MAJOR [IN/16][NN][16] from previous gather.
// Output h: bf16 SLICE-MAJOR [OUT/16][NN][16]. BN scale/shift inline from
// NREP-replicated partials. GAT bias b cancels under BN. W staged once/block,
// reused across GRP node-groups.

template <int IN, int OUT, bool BN, int GRP>
__global__ void k_transform(const void* __restrict__ xv, const float* __restrict__ W,
                            const float* __restrict__ a_src, const float* __restrict__ a_dst,
                            const float* __restrict__ bnrep,   // [NREP][2*IN]
                            const float* __restrict__ gamma, const float* __restrict__ beta,
                            unsigned short* __restrict__ h, float* __restrict__ als,
                            float* __restrict__ ald, int n) {
    constexpr int C = OUT / 2;       // channels per head
    constexpr int TPN = OUT / 4;     // threads per node (4 ch per thread)
    constexpr int NB = 256 / TPN;    // nodes per group
    __shared__ float4 Ws4[IN * TPN];
    __shared__ float xs[NB * IN];
    __shared__ float sbn[BN ? 2 * IN : 1];

    if constexpr (BN) {
        if (threadIdx.x < IN) {
            int c = threadIdx.x;
            float s = 0.f, ss = 0.f;
#pragma unroll
            for (int r = 0; r < NREP; ++r) {
                s  += bnrep[r * 2 * IN + c];
                ss += bnrep[r * 2 * IN + IN + c];
            }
            float mu = s / n;
            float var = ss / n - mu * mu;
            float sca = gamma[c] * rsqrtf(var + EPS);
            sbn[c] = sca;
            sbn[IN + c] = beta[c] - mu * sca;
        }
    }
    float* Wsf = (float*)Ws4;
    for (int i = threadIdx.x; i < IN * OUT; i += 256) Wsf[i] = W[i];
    __syncthreads();

    int nl = threadIdx.x / TPN, q = threadIdx.x % TPN;
    int hd = (q >= TPN / 2);
    int cc = (q - hd * (TPN / 2)) * 4;
    float4 as4 = *(const float4*)&a_src[hd * C + cc];
    float4 ad4 = *(const float4*)&a_dst[hd * C + cc];

    for (int g = 0; g < GRP; ++g) {
        int node0 = (blockIdx.x * GRP + g) * NB;
        if (node0 >= n) break;
        if constexpr (BN) {
            // bf16 slice-major input: uints [IN/16][NN][8]
            const unsigned* xu = (const unsigned*)xv;
            for (int i = threadIdx.x; i < NB * IN / 2; i += 256) {
                int s = i / (NB * 8);
                int r = i % (NB * 8);
                int node = r >> 3, pr = r & 7;
                int nn = node0 + node;
                unsigned u = (nn < n) ? xu[(size_t)s * NN * 8 + (size_t)nn * 8 + pr] : 0u;
                int c0 = s * 16 + pr * 2;
                float v0 = bflo(u) * sbn[c0] + sbn[IN + c0];
                float v1 = bfhi(u) * sbn[c0 + 1] + sbn[IN + c0 + 1];
                xs[node * IN + c0]     = v0 > 0.f ? v0 : 0.f;
                xs[node * IN + c0 + 1] = v1 > 0.f ? v1 : 0.f;
            }
        } else {
            const float* x = (const float*)xv;
            for (int i = threadIdx.x; i < NB * IN; i += 256) {
                int nn = node0 + i / IN;
                xs[i] = (nn < n) ? x[(size_t)nn * IN + (i % IN)] : 0.f;
            }
        }
        __syncthreads();
        int node = node0 + nl;
        float4 acc = {0.f, 0.f, 0.f, 0.f};
#pragma unroll
        for (int i = 0; i < IN; ++i) {
            float xv2 = xs[nl * IN + i];
            float4 w = Ws4[i * TPN + q];
            acc.x += xv2 * w.x; acc.y += xv2 * w.y; acc.z += xv2 * w.z; acc.w += xv2 * w.w;
        }
        if (node < n) {
            // slice-major write: channel base q*4 -> slice q>>2, offset (q&3)*4
            uint2 pk;
            pk.x = (unsigned)f2bf(acc.x) | ((unsigned)f2bf(acc.y) << 16);
            pk.y = (unsigned)f2bf(acc.z) | ((unsigned)f2bf(acc.w) << 16);
            *(uint2*)&h[(size_t)(q >> 2) * NN * 16 + (size_t)node * 16 + (q & 3) * 4] = pk;
        }
        float ps = acc.x * as4.x + acc.y * as4.y + acc.z * as4.z + acc.w * as4.w;
        float pd = acc.x * ad4.x + acc.y * ad4.y + acc.z * ad4.z + acc.w * ad4.w;
#pragma unroll
        for (int m = 1; m < TPN / 2; m <<= 1) {
            ps += __shfl_xor(ps, m, 64);
            pd += __shfl_xor(pd, m, 64);
        }
        if ((q & (TPN / 2 - 1)) == 0 && node < n) {
            als[node * 2 + hd] = ps;
            ald[node * 2 + hd] = pd;
        }
        __syncthreads();   // xs reused next group
    }
}

// ---------------- Alpha: normalized softmax weight per edge (both heads) ----------------
// Two dst nodes per wave (half-wave each), cnt<=32 fast path; generic fallback.
// alpha layout: [2][TE] fp32, coalesced writes.

__device__ __forceinline__ float lrelu(float v) { return v > 0.f ? v : NEG_SLOPE * v; }

__global__ void k_alpha(const int* __restrict__ rowptr, const int* __restrict__ colsrc,
                        const float* __restrict__ als, const float* __restrict__ ald,
                        float* __restrict__ alpha) {
    int wv = threadIdx.x >> 6;
    int lane = threadIdx.x & 63;
    int hw = lane >> 5, hl = lane & 31;
    int base = ((int)blockIdx.x * 4 + wv) * 2;
    int wid = base + hw;
    bool valid = wid < NN;
    int start = 0, cnt = 0;
    float2 dv = make_float2(0.f, 0.f);
    if (valid) {
        start = rowptr[wid];
        cnt = rowptr[wid + 1] - start;
        dv = ((const float2*)ald)[wid];
    }
    int mc = max(cnt, __shfl_xor(cnt, 32, 64));

    if (mc <= 32) {
        int e = start + hl;
        bool act = valid && (hl < cnt);
        int s = act ? colsrc[e] : 0;
        float2 av = act ? ((const float2*)als)[s] : make_float2(0.f, 0.f);
        float t0 = act ? lrelu(av.x + dv.x) : -1e30f;
        float t1 = act ? lrelu(av.y + dv.y) : -1e30f;
        float m0 = t0, m1 = t1;
#pragma unroll
        for (int off = 16; off; off >>= 1) {
            m0 = fmaxf(m0, __shfl_xor(m0, off, 32));
            m1 = fmaxf(m1, __shfl_xor(m1, off, 32));
        }
        float w0 = act ? __expf(t0 - m0) : 0.f;
        float w1 = act ? __expf(t1 - m1) : 0.f;
        float den0 = w0, den1 = w1;
#pragma unroll
        for (int off = 16; off; off >>= 1) {
            den0 += __shfl_xor(den0, off, 32);
            den1 += __shfl_xor(den1, off, 32);
        }
        if (act) {
            alpha[e] = w0 / den0;
            alpha[TE + e] = w1 / den1;
        }
    } else {
        for (int i = 0; i < 2; ++i) {
            int w2 = base + i;
            if (w2 >= NN) continue;
            int st = rowptr[w2], en = rowptr[w2 + 1];
            float2 dv2 = ((const float2*)ald)[w2];
            float m0 = -1e30f, m1 = -1e30f;
            for (int e = st + lane; e < en; e += 64) {
                int s = colsrc[e];
                float t0 = lrelu(als[s * 2 + 0] + dv2.x);
                float t1 = lrelu(als[s * 2 + 1] + dv2.y);
                m0 = fmaxf(m0, t0); m1 = fmaxf(m1, t1);
            }
#pragma unroll
            for (int off = 32; off; off >>= 1) {
                m0 = fmaxf(m0, __shfl_xor(m0, off, 64));
                m1 = fmaxf(m1, __shfl_xor(m1, off, 64));
            }
            float den0 = 0.f, den1 = 0.f;
            for (int e = st + lane; e < en; e += 64) {
                int s = colsrc[e];
                den0 += __expf(lrelu(als[s * 2 + 0] + dv2.x) - m0);
                den1 += __expf(lrelu(als[s * 2 + 1] + dv2.y) - m1);
            }
#pragma unroll
            for (int off = 32; off; off >>= 1) {
                den0 += __shfl_xor(den0, off, 64);
                den1 += __shfl_xor(den1, off, 64);
            }
            float inv0 = 1.f / den0, inv1 = 1.f / den1;
            for (int e = st + lane; e < en; e += 64) {
                int s = colsrc[e];
                alpha[e] = __expf(lrelu(als[s * 2 + 0] + dv2.x) - m0) * inv0;
                alpha[TE + e] = __expf(lrelu(als[s * 2 + 1] + dv2.y) - m1) * inv1;
            }
        }
    }
}

// ---------------- Gather: channel-sliced, XCD-L2-resident ----------------
// grid = nchunks * NSLICE, slice = blockIdx % NSLICE. With round-robin
// block->XCD dispatch, each XCD touches only a 3.2 MB h-slice (fits 4 MiB L2).
// h and out are slice-major [NSLICE][NN][16]. Half-wave per dst node:
// 16 edge slots x 2 lanes (16B each). Any degree handled by the j-loop.

template <int OUT>
__global__ void k_gather(const int* __restrict__ rowptr, const int* __restrict__ colsrc,
                         const unsigned short* __restrict__ h, const float* __restrict__ alpha,
                         unsigned short* __restrict__ out, float* __restrict__ bnrep) {
    constexpr int NSLICE = OUT / 16;
    __shared__ float rowbuf[8][16];
    int slice = blockIdx.x % NSLICE;
    int chunk = blockIdx.x / NSLICE;
    int head = (slice * 32) / OUT;
    const unsigned short* hsl = h + (size_t)slice * NN * 16;
    unsigned short* osl = out + (size_t)slice * NN * 16;
    const float* al = alpha + (size_t)head * TE;
    int wv = threadIdx.x >> 6, lane = threadIdx.x & 63;
    int hw = lane >> 5, hl = lane & 31;
    int hwIdx = wv * 2 + hw;             // 0..7
    int node = chunk * 8 + hwIdx;
    int j = hl & 15, p = hl >> 4;        // edge slot, 16B parity
    float acc[8];
#pragma unroll
    for (int k = 0; k < 8; ++k) acc[k] = 0.f;

    if (node < NN) {
        int start = rowptr[node], cnt = rowptr[node + 1] - start;
        for (int j0 = 0; j0 < cnt; j0 += 16) {
            int jj = j0 + j;
            if (jj < cnt) {
                int e = start + jj;
                int s = colsrc[e];
                float a = al[e];
                uint4 hv = *(const uint4*)&hsl[(size_t)s * 16 + p * 8];
                acc[0] += a * bflo(hv.x); acc[1] += a * bfhi(hv.x);
                acc[2] += a * bflo(hv.y); acc[3] += a * bfhi(hv.y);
                acc[4] += a * bflo(hv.z); acc[5] += a * bfhi(hv.z);
                acc[6] += a * bflo(hv.w); acc[7] += a * bfhi(hv.w);
            }
        }
        // reduce over the 16 edge slots (xor masks stay within the 16-group)
#pragma unroll
        for (int m = 1; m < 16; m <<= 1) {
#pragma unroll
            for (int k = 0; k < 8; ++k) acc[k] += __shfl_xor(acc[k], m, 64);
        }
        if (j == 0) {
            uint4 pk;
            pk.x = (unsigned)f2bf(acc[0]) | ((unsigned)f2bf(acc[1]) << 16);
            pk.y = (unsigned)f2bf(acc[2]) | ((unsigned)f2bf(acc[3]) << 16);
            pk.z = (unsigned)f2bf(acc[4]) | ((unsigned)f2bf(acc[5]) << 16);
            pk.w = (unsigned)f2bf(acc[6]) | ((unsigned)f2bf(acc[7]) << 16);
            *(uint4*)&osl[(size_t)node * 16 + p * 8] = pk;
#pragma unroll
            for (int k = 0; k < 8; ++k) rowbuf[hwIdx][p * 8 + k] = acc[k];
        }
    } else if (j == 0) {
#pragma unroll
        for (int k = 0; k < 8; ++k) rowbuf[hwIdx][p * 8 + k] = 0.f;
    }
    __syncthreads();
    // BN partials for this slice's 16 channels over the block's 8 nodes
    if (threadIdx.x < 16) {
        float s = 0.f, ss = 0.f;
#pragma unroll
        for (int r = 0; r < 8; ++r) {
            float v = rowbuf[r][threadIdx.x];
            s += v; ss += v * v;
        }
        float* dst = &bnrep[(chunk & (NREP - 1)) * 2 * OUT];
        atomicAdd(&dst[slice * 16 + threadIdx.x], s);
        atomicAdd(&dst[OUT + slice * 16 + threadIdx.x], ss);
    }
}

// ---------------- Pooling (BN3 inline + ReLU) + FC ----------------
// h1 is slice-major [8][NN][16]. Post-ReLU >= 0 so atomicMax(int) with 0-init ok.

__global__ void k_pool(const unsigned short* __restrict__ h, const int* __restrict__ batch,
                       const float* __restrict__ bnrep, const float* __restrict__ gamma,
                       const float* __restrict__ beta, float* __restrict__ pooled, int n) {
    const int K = 32;               // nodes per block
    int c = threadIdx.x;            // 0..127
    float s = 0.f, ss = 0.f;
#pragma unroll
    for (int r = 0; r < NREP; ++r) {
        s  += bnrep[r * 256 + c];
        ss += bnrep[r * 256 + 128 + c];
    }
    float mu = s / n;
    float var = ss / n - mu * mu;
    float scale = gamma[c] * rsqrtf(var + EPS);
    float shift = beta[c] - mu * scale;
    const unsigned short* hc = h + (size_t)(c >> 4) * NN * 16 + (c & 15);
    int n0 = blockIdx.x * K;
    if (n0 >= n) return;
    int nend = min(n, n0 + K);
    int curg = batch[n0];
    float m = 0.f;
    for (int nn = n0; nn < nend; ++nn) {
        int g = batch[nn];
        if (g != curg) {
            atomicMax((int*)&pooled[curg * 128 + c], __float_as_int(m));
            m = 0.f; curg = g;
        }
        float v = bf2f(hc[(size_t)nn * 16]) * scale + shift;
        m = fmaxf(m, v > 0.f ? v : 0.f);
    }
    atomicMax((int*)&pooled[curg * 128 + c], __float_as_int(m));
}

__global__ void k_fc(const float* __restrict__ pooled, const float* __restrict__ fcw,
                     const float* __restrict__ fcb, float* __restrict__ out) {
    int t = threadIdx.x;
    if (t >= NG * 10) return;
    int g = t / 10, j = t % 10;
    float acc = fcb[j];
#pragma unroll
    for (int c = 0; c < 128; ++c) acc += pooled[g * 128 + c] * fcw[c * 10 + j];
    out[g * 10 + j] = acc;
}

// ---------------- Host launch ----------------

extern "C" void kernel_launch(void* const* d_in, const int* in_sizes, int n_in,
                              void* d_out, int out_size, void* d_ws, size_t ws_size,
                              hipStream_t stream) {
    const float* x   = (const float*)d_in[0];
    const int*   ei  = (const int*)d_in[1];
    const int*   bat = (const int*)d_in[2];
    const float* W1  = (const float*)d_in[3];
    const float* as1 = (const float*)d_in[4];
    const float* ad1 = (const float*)d_in[5];
    // d_in[6] = b1 (cancels under BN)
    const float* g1  = (const float*)d_in[7];
    const float* be1 = (const float*)d_in[8];
    const float* W2  = (const float*)d_in[9];
    const float* as2 = (const float*)d_in[10];
    const float* ad2 = (const float*)d_in[11];
    const float* g2  = (const float*)d_in[13];
    const float* be2 = (const float*)d_in[14];
    const float* W3  = (const float*)d_in[15];
    const float* as3 = (const float*)d_in[16];
    const float* ad3 = (const float*)d_in[17];
    const float* g3  = (const float*)d_in[19];
    const float* be3 = (const float*)d_in[20];
    const float* fcw = (const float*)d_in[21];
    const float* fcb = (const float*)d_in[22];
    float* out = (float*)d_out;

    char* w = (char*)d_ws;
    size_t off = 0;
    auto take = [&](size_t bytes) {
        void* p = w + off;
        off += (bytes + 255) & ~(size_t)255;
        return p;
    };
    // ---- single zero-init region: bnrep1/2/3 | pooled ----
    constexpr size_t ZN = (size_t)NREP * 2 * (32 + 64 + 128) + NG * 128;
    char* zreg = (char*)take(ZN * 4);
    float* bnr1   = (float*)zreg;                    // NREP*64
    float* bnr2   = bnr1 + NREP * 64;                // NREP*128
    float* bnr3   = bnr2 + NREP * 128;               // NREP*256
    float* pooled = bnr3 + NREP * 256;               // NG*128

    int*   hist    = (int*)take((size_t)NBUCK * PHB * 4);
    int*   bsum    = (int*)take(NBUCK * 4);
    int*   bbase   = (int*)take((NBUCK + 1) * 4);
    int*   rowptr  = (int*)take((size_t)(NN + 1) * 4);
    int*   pairs   = (int*)take((size_t)TE * 4);
    int*   colsrc  = (int*)take((size_t)TE * 4);
    float* al_s    = (float*)take((size_t)NN * 2 * 4);
    float* al_d    = (float*)take((size_t)NN * 2 * 4);
    float* alpha   = (float*)take((size_t)2 * TE * 4);
    unsigned short* h0 = (unsigned short*)take((size_t)NN * 128 * 2);  // bf16 slice-major
    unsigned short* h1 = (unsigned short*)take((size_t)NN * 128 * 2);  // bf16 slice-major

    hipMemsetAsync(zreg, 0, ZN * 4, stream);

    // ---- CSR build (bucketed counting sort) ----
    k_hist<<<PHB, 256, 0, stream>>>(ei, hist);
    k_scanA<<<NBUCK, PHB, 0, stream>>>(hist, bsum);
    k_scanB<<<1, NBUCK, 0, stream>>>(bsum, bbase, rowptr);
    k_scatter<<<PHB, 256, 0, stream>>>(ei, hist, bbase, pairs);
    k_csr<<<NBUCK, 256, 0, stream>>>(pairs, bbase, rowptr, colsrc);

    const int ALPHA_BLOCKS = (NN + 7) / 8;     // 8 nodes/block
    const int NCHUNK = (NN + 7) / 8;           // 8 nodes/block in gather

    // ---- layer 1: 3 -> 32 (H=2, C=16), NSLICE=2 ----
    k_transform<3, 32, false, 1><<<(NN + 31) / 32, 256, 0, stream>>>(
        x, W1, as1, ad1, nullptr, nullptr, nullptr, h0, al_s, al_d, NN);
    k_alpha<<<ALPHA_BLOCKS, 256, 0, stream>>>(rowptr, colsrc, al_s, al_d, alpha);
    k_gather<32><<<NCHUNK * 2, 256, 0, stream>>>(rowptr, colsrc, h0, alpha, h1, bnr1);

    // ---- layer 2: 32 -> 64 (H=2, C=32), NSLICE=4 ----
    k_transform<32, 64, true, 4><<<(NN + 63) / 64, 256, 0, stream>>>(
        h1, W2, as2, ad2, bnr1, g1, be1, h0, al_s, al_d, NN);
    k_alpha<<<ALPHA_BLOCKS, 256, 0, stream>>>(rowptr, colsrc, al_s, al_d, alpha);
    k_gather<64><<<NCHUNK * 4, 256, 0, stream>>>(rowptr, colsrc, h0, alpha, h1, bnr2);

    // ---- layer 3: 64 -> 128 (H=2, C=64), NSLICE=8 ----
    k_transform<64, 128, true, 4><<<(NN + 31) / 32, 256, 0, stream>>>(
        h1, W3, as3, ad3, bnr2, g2, be2, h0, al_s, al_d, NN);
    k_alpha<<<ALPHA_BLOCKS, 256, 0, stream>>>(rowptr, colsrc, al_s, al_d, alpha);
    k_gather<128><<<NCHUNK * 8, 256, 0, stream>>>(rowptr, colsrc, h0, alpha, h1, bnr3);

    // ---- pool (BN3 inline) + fc ----
    k_pool<<<(NN + 31) / 32, 128, 0, stream>>>(h1, bat, bnr3, g3, be3, pooled, NN);
    k_fc<<<1, 640, 0, stream>>>(pooled, fcw, fcb, out);
}

// Round 10
// 358.734 us; speedup vs baseline: 1.3753x; 1.3753x over previous
//
#include <hip/hip_runtime.h>
#include <cstddef>

// Problem constants (fixed by the reference setup)
constexpr int NN = 100000;          // nodes
constexpr int NE = 1600000;         // edges (without self loops)
constexpr int TE = NE + NN;         // edges + self loops = 1,700,000
constexpr int NG = 64;              // graphs
constexpr float EPS = 1e-5f;
constexpr float NEG_SLOPE = 0.2f;
constexpr int NREP = 16;            // BN partial-sum replicas

// CSR bucket sort parameters
constexpr int NBUCK = 256;          // dst buckets
constexpr int DPB = 391;            // dsts per bucket (256*391 >= NN)
constexpr int PHB = 256;            // edge-chunk blocks
constexpr int CH = (TE + PHB - 1) / PHB;   // edges per chunk

// bf16 helpers (RNE pack, exact unpack)
__device__ __forceinline__ unsigned short f2bf(float f) {
    unsigned u = __float_as_uint(f);
    u += 0x7fffu + ((u >> 16) & 1u);
    return (unsigned short)(u >> 16);
}
__device__ __forceinline__ float bf2f(unsigned short s) {
    return __uint_as_float((unsigned)s << 16);
}
__device__ __forceinline__ float bflo(unsigned u) { return __uint_as_float(u << 16); }
__device__ __forceinline__ float bfhi(unsigned u) { return __uint_as_float(u & 0xffff0000u); }

// ---------------- CSR build: bucketed counting sort ----------------

__global__ void k_hist(const int* __restrict__ ei, int* __restrict__ hist) {
    __shared__ int hcnt[NBUCK];
    for (int i = threadIdx.x; i < NBUCK; i += 256) hcnt[i] = 0;
    __syncthreads();
    int k = blockIdx.x;
    int e0 = k * CH, e1 = min(e0 + CH, TE);
    for (int e = e0 + threadIdx.x; e < e1; e += 256) {
        int d = (e < NE) ? ei[NE + e] : (e - NE);
        atomicAdd(&hcnt[d / DPB], 1);
    }
    __syncthreads();
    for (int b = threadIdx.x; b < NBUCK; b += 256) hist[b * PHB + k] = hcnt[b];
}

__global__ void k_scanA(int* __restrict__ hist, int* __restrict__ bsum) {
    __shared__ int ls[PHB];
    int b = blockIdx.x, t = threadIdx.x;
    int v = hist[b * PHB + t];
    ls[t] = v;
    __syncthreads();
    for (int off = 1; off < PHB; off <<= 1) {
        int add = (t >= off) ? ls[t - off] : 0;
        __syncthreads();
        ls[t] += add;
        __syncthreads();
    }
    hist[b * PHB + t] = ls[t] - v;      // exclusive
    if (t == PHB - 1) bsum[b] = ls[t];  // bucket total
}

__global__ void k_scanB(const int* __restrict__ bsum, int* __restrict__ bbase,
                        int* __restrict__ rowptr) {
    __shared__ int ls[NBUCK];
    int t = threadIdx.x;
    int v = bsum[t];
    ls[t] = v;
    __syncthreads();
    for (int off = 1; off < NBUCK; off <<= 1) {
        int add = (t >= off) ? ls[t - off] : 0;
        __syncthreads();
        ls[t] += add;
        __syncthreads();
    }
    bbase[t] = ls[t] - v;
    if (t == NBUCK - 1) { bbase[NBUCK] = ls[t]; rowptr[NN] = ls[t]; }  // == TE
}

__global__ void k_scatter(const int* __restrict__ ei, const int* __restrict__ hist,
                          const int* __restrict__ bbase, int* __restrict__ pairs) {
    __shared__ int cur[NBUCK];
    int k = blockIdx.x;
    for (int b = threadIdx.x; b < NBUCK; b += 256) cur[b] = bbase[b] + hist[b * PHB + k];
    __syncthreads();
    int e0 = k * CH, e1 = min(e0 + CH, TE);
    for (int e = e0 + threadIdx.x; e < e1; e += 256) {
        int s, d;
        if (e < NE) { s = ei[e]; d = ei[NE + e]; } else { s = e - NE; d = s; }
        int b = d / DPB, ld = d - b * DPB;
        int pos = atomicAdd(&cur[b], 1);
        pairs[pos] = (s << 9) | ld;
    }
}

__global__ void k_csr(const int* __restrict__ pairs, const int* __restrict__ bbase,
                      int* __restrict__ rowptr, int* __restrict__ colsrc) {
    __shared__ int deg[DPB];     // counts, then reused as cursors
    __shared__ int exc[DPB];     // exclusive scan
    __shared__ int sc[512];
    int b = blockIdx.x, t = threadIdx.x;
    int base = bbase[b], cnt = bbase[b + 1] - base;
    int d0 = b * DPB;
    int ndst = min(DPB, NN - d0);
    for (int i = t; i < DPB; i += 256) deg[i] = 0;
    __syncthreads();
    for (int i = t; i < cnt; i += 256) atomicAdd(&deg[pairs[base + i] & 511], 1);
    __syncthreads();
    sc[t] = (t < DPB) ? deg[t] : 0;
    sc[t + 256] = (t + 256 < DPB) ? deg[t + 256] : 0;
    __syncthreads();
    for (int off = 1; off < 512; off <<= 1) {
        int a0 = (t >= off) ? sc[t - off] : 0;
        int a1 = (t + 256 >= off) ? sc[t + 256 - off] : 0;
        __syncthreads();
        sc[t] += a0; sc[t + 256] += a1;
        __syncthreads();
    }
    if (t < DPB) exc[t] = sc[t] - deg[t];
    if (t + 256 < DPB) exc[t + 256] = sc[t + 256] - deg[t + 256];
    __syncthreads();
    for (int i = t; i < ndst; i += 256) rowptr[d0 + i] = base + exc[i];
    for (int i = t; i < DPB; i += 256) deg[i] = 0;   // reuse as cursor
    __syncthreads();
    for (int i = t; i < cnt; i += 256) {
        int p = pairs[base + i];
        int ld = p & 511;
        int s = (unsigned)p >> 9;
        int pos = base + exc[ld] + atomicAdd(&deg[ld], 1);
        colsrc[pos] = s;
    }
}

// ---------------- Node transform: h = bnrelu(x) @ W ; attention dots ----------------
// W staged once per block, reused across GRP node-groups. BN scale/shift inline
// from NREP-replicated partials (L2-hot). GAT bias b cancels under BN.

template <int IN, int OUT, bool BN, int GRP>
__global__ void k_transform(const void* __restrict__ xv, const float* __restrict__ W,
                            const float* __restrict__ a_src, const float* __restrict__ a_dst,
                            const float* __restrict__ bnrep,   // [NREP][2*IN] partials
                            const float* __restrict__ gamma, const float* __restrict__ beta,
                            unsigned short* __restrict__ h, float* __restrict__ als,
                            float* __restrict__ ald, int n) {
    constexpr int C = OUT / 2;       // channels per head
    constexpr int TPN = OUT / 4;     // threads per node (float4 per thread)
    constexpr int NB = 256 / TPN;    // nodes per group
    __shared__ float4 Ws4[IN * TPN];
    __shared__ float xs[NB * IN];
    __shared__ float sbn[BN ? 2 * IN : 1];

    if constexpr (BN) {
        if (threadIdx.x < IN) {
            int c = threadIdx.x;
            float s = 0.f, ss = 0.f;
#pragma unroll
            for (int r = 0; r < NREP; ++r) {
                s  += bnrep[r * 2 * IN + c];
                ss += bnrep[r * 2 * IN + IN + c];
            }
            float mu = s / n;
            float var = ss / n - mu * mu;
            float sca = gamma[c] * rsqrtf(var + EPS);
            sbn[c] = sca;
            sbn[IN + c] = beta[c] - mu * sca;
        }
    }
    float* Wsf = (float*)Ws4;
    for (int i = threadIdx.x; i < IN * OUT; i += 256) Wsf[i] = W[i];
    __syncthreads();

    int nl = threadIdx.x / TPN, q = threadIdx.x % TPN;
    int hd = (q >= TPN / 2);
    int cc = (q - hd * (TPN / 2)) * 4;
    float4 as4 = *(const float4*)&a_src[hd * C + cc];
    float4 ad4 = *(const float4*)&a_dst[hd * C + cc];

    for (int g = 0; g < GRP; ++g) {
        int node0 = (blockIdx.x * GRP + g) * NB;
        if (node0 >= n) break;
        if constexpr (BN) {
            const unsigned* xu = (const unsigned*)xv + (size_t)node0 * IN / 2;
            for (int i = threadIdx.x; i < NB * IN / 2; i += 256) {
                int e0 = 2 * i;
                int nn = node0 + e0 / IN;
                unsigned u = (nn < n) ? xu[i] : 0u;
                int c0 = e0 % IN;
                float v0 = bflo(u) * sbn[c0] + sbn[IN + c0];
                float v1 = bfhi(u) * sbn[c0 + 1] + sbn[IN + c0 + 1];
                xs[e0]     = v0 > 0.f ? v0 : 0.f;
                xs[e0 + 1] = v1 > 0.f ? v1 : 0.f;
            }
        } else {
            const float* x = (const float*)xv;
            for (int i = threadIdx.x; i < NB * IN; i += 256) {
                int nn = node0 + i / IN;
                xs[i] = (nn < n) ? x[(size_t)nn * IN + (i % IN)] : 0.f;
            }
        }
        __syncthreads();
        int node = node0 + nl;
        float4 acc = {0.f, 0.f, 0.f, 0.f};
#pragma unroll
        for (int i = 0; i < IN; ++i) {
            float xv2 = xs[nl * IN + i];
            float4 w = Ws4[i * TPN + q];
            acc.x += xv2 * w.x; acc.y += xv2 * w.y; acc.z += xv2 * w.z; acc.w += xv2 * w.w;
        }
        if (node < n) {
            uint2 pk;
            pk.x = (unsigned)f2bf(acc.x) | ((unsigned)f2bf(acc.y) << 16);
            pk.y = (unsigned)f2bf(acc.z) | ((unsigned)f2bf(acc.w) << 16);
            *(uint2*)&h[(size_t)node * OUT + q * 4] = pk;
        }
        float ps = acc.x * as4.x + acc.y * as4.y + acc.z * as4.z + acc.w * as4.w;
        float pd = acc.x * ad4.x + acc.y * ad4.y + acc.z * ad4.z + acc.w * ad4.w;
#pragma unroll
        for (int m = 1; m < TPN / 2; m <<= 1) {
            ps += __shfl_xor(ps, m, 64);
            pd += __shfl_xor(pd, m, 64);
        }
        if ((q & (TPN / 2 - 1)) == 0 && node < n) {
            als[node * 2 + hd] = ps;
            ald[node * 2 + hd] = pd;
        }
        __syncthreads();   // xs reused next group
    }
}

// ---------------- Aggregation: TWO dst nodes per wave (half-wave each) ----------------
// Fast path cnt<=32 per node; gather loop unrolled x4 with clamped unconditional
// loads -> 4 independent global_load_dwordx4 in flight per lane (MLP for the
// latency-bound random gather). Tail slots get weight 0 and a repeated (cached)
// address. Rare deg>32 falls back to a 64-lane generic path.

__device__ __forceinline__ float lrelu(float v) { return v > 0.f ? v : NEG_SLOPE * v; }

template <int OUT>
__global__ void k_aggregate(const int* __restrict__ rowptr, const int* __restrict__ colsrc,
                            const unsigned short* __restrict__ h, const float* __restrict__ als,
                            const float* __restrict__ ald, unsigned short* __restrict__ out,
                            float* __restrict__ bnrep) {
    constexpr int LPE = OUT / 8;    // lanes per edge (8 bf16 = 16B per lane)
    constexpr int EPI2 = 32 / LPE;  // edges per iteration per half-wave
    constexpr int UNR = 4;          // gather unroll (MLP)
    __shared__ float rowbuf[8][OUT];
    __shared__ float4 etab[4][64];   // per-wave edge table {s, w0, w1, -}
    int wv = threadIdx.x >> 6;
    int lane = threadIdx.x & 63;
    int hw = lane >> 5, hl = lane & 31;
    int base = ((int)blockIdx.x * 4 + wv) * 2;   // first node of this wave
    int wid = base + hw;                          // node handled by this half
    bool valid = wid < NN;

    int start = 0, cnt = 0;
    float2 dv = make_float2(0.f, 0.f);
    if (valid) {
        start = rowptr[wid];
        cnt = rowptr[wid + 1] - start;
        dv = ((const float2*)ald)[wid];
    }
    int mc = max(cnt, __shfl_xor(cnt, 32, 64));   // wave-uniform max cnt

    if (mc <= 32) {
        // ---- fast path: each half-wave owns one node ----
        int e = start + hl;
        bool act = valid && (hl < cnt);
        int s = act ? colsrc[e] : 0;
        float2 av = act ? ((const float2*)als)[s] : make_float2(0.f, 0.f);
        float t0 = act ? lrelu(av.x + dv.x) : -1e30f;
        float t1 = act ? lrelu(av.y + dv.y) : -1e30f;
        float m0 = t0, m1 = t1;
#pragma unroll
        for (int off = 16; off; off >>= 1) {
            m0 = fmaxf(m0, __shfl_xor(m0, off, 32));
            m1 = fmaxf(m1, __shfl_xor(m1, off, 32));
        }
        float w0 = act ? __expf(t0 - m0) : 0.f;
        float w1 = act ? __expf(t1 - m1) : 0.f;
        float den0 = w0, den1 = w1;
#pragma unroll
        for (int off = 16; off; off >>= 1) {
            den0 += __shfl_xor(den0, off, 32);
            den1 += __shfl_xor(den1, off, 32);
        }
        etab[wv][lane] = make_float4(__int_as_float(s), w0, w1, 0.f);
        int sub = hl / LPE, cl = hl % LPE;
        bool head1 = (cl >= LPE / 2);
        float acc[8];
#pragma unroll
        for (int k = 0; k < 8; ++k) acc[k] = 0.f;
        if (valid) {
            int cm1 = cnt - 1;
            for (int j0 = 0; j0 < cnt; j0 += EPI2 * UNR) {
                float wsl[UNR];
                uint4 hv[UNR];
#pragma unroll
                for (int u = 0; u < UNR; ++u) {
                    int jj = j0 + u * EPI2 + sub;
                    int jc = min(jj, cm1);               // always a valid edge
                    float4 ed = etab[wv][hw * 32 + jc];
                    wsl[u] = (jj <= cm1) ? (head1 ? ed.z : ed.y) : 0.f;
                    hv[u] = *(const uint4*)&h[(size_t)__float_as_int(ed.x) * OUT + cl * 8];
                }
#pragma unroll
                for (int u = 0; u < UNR; ++u) {
                    float a = wsl[u];
                    acc[0] += a * bflo(hv[u].x); acc[1] += a * bfhi(hv[u].x);
                    acc[2] += a * bflo(hv[u].y); acc[3] += a * bfhi(hv[u].y);
                    acc[4] += a * bflo(hv[u].z); acc[5] += a * bfhi(hv[u].z);
                    acc[6] += a * bflo(hv[u].w); acc[7] += a * bfhi(hv[u].w);
                }
            }
        }
#pragma unroll
        for (int m = LPE; m < 32; m <<= 1) {
#pragma unroll
            for (int k = 0; k < 8; ++k) acc[k] += __shfl_xor(acc[k], m, 32);
        }
        float inv = 1.f / (head1 ? den1 : den0);
        if (valid && sub == 0) {
            float o[8];
#pragma unroll
            for (int k = 0; k < 8; ++k) o[k] = acc[k] * inv;
            uint4 pk;
            pk.x = (unsigned)f2bf(o[0]) | ((unsigned)f2bf(o[1]) << 16);
            pk.y = (unsigned)f2bf(o[2]) | ((unsigned)f2bf(o[3]) << 16);
            pk.z = (unsigned)f2bf(o[4]) | ((unsigned)f2bf(o[5]) << 16);
            pk.w = (unsigned)f2bf(o[6]) | ((unsigned)f2bf(o[7]) << 16);
            *(uint4*)&out[(size_t)wid * OUT + cl * 8] = pk;
            *(float4*)&rowbuf[wv * 2 + hw][cl * 8] = make_float4(o[0], o[1], o[2], o[3]);
            *(float4*)&rowbuf[wv * 2 + hw][cl * 8 + 4] = make_float4(o[4], o[5], o[6], o[7]);
        } else if (!valid) {
            for (int c = hl; c < OUT; c += 32) rowbuf[wv * 2 + hw][c] = 0.f;
        }
    } else {
        // ---- rare fallback: whole wave processes each node generically ----
        for (int i = 0; i < 2; ++i) {
            int w2 = base + i;
            int rb = wv * 2 + i;
            if (w2 >= NN) {
                for (int c = lane; c < OUT; c += 64) rowbuf[rb][c] = 0.f;
                continue;
            }
            int st = rowptr[w2], en = rowptr[w2 + 1];
            float2 dv2 = ((const float2*)ald)[w2];
            constexpr int C = OUT / 2;
            float m0 = -1e30f, m1 = -1e30f;
            for (int e = st + lane; e < en; e += 64) {
                int s = colsrc[e];
                float t0 = lrelu(als[s * 2 + 0] + dv2.x);
                float t1 = lrelu(als[s * 2 + 1] + dv2.y);
                m0 = fmaxf(m0, t0); m1 = fmaxf(m1, t1);
            }
#pragma unroll
            for (int off = 32; off; off >>= 1) {
                m0 = fmaxf(m0, __shfl_xor(m0, off, 64));
                m1 = fmaxf(m1, __shfl_xor(m1, off, 64));
            }
            float den0 = 0.f, den1 = 0.f;
            for (int e = st + lane; e < en; e += 64) {
                int s = colsrc[e];
                float t0 = lrelu(als[s * 2 + 0] + dv2.x);
                float t1 = lrelu(als[s * 2 + 1] + dv2.y);
                den0 += __expf(t0 - m0); den1 += __expf(t1 - m1);
            }
#pragma unroll
            for (int off = 32; off; off >>= 1) {
                den0 += __shfl_xor(den0, off, 64);
                den1 += __shfl_xor(den1, off, 64);
            }
            float inv0 = 1.f / den0, inv1 = 1.f / den1;
            if constexpr (OUT == 128) {
                float a0 = 0.f, a1 = 0.f;
                for (int e = st; e < en; ++e) {
                    int s = colsrc[e];
                    float t0 = lrelu(als[s * 2 + 0] + dv2.x);
                    float t1 = lrelu(als[s * 2 + 1] + dv2.y);
                    float w0 = __expf(t0 - m0) * inv0;
                    float w1 = __expf(t1 - m1) * inv1;
                    a0 += w0 * bf2f(h[(size_t)s * OUT + lane]);
                    a1 += w1 * bf2f(h[(size_t)s * OUT + 64 + lane]);
                }
                out[(size_t)w2 * OUT + lane] = f2bf(a0);
                out[(size_t)w2 * OUT + 64 + lane] = f2bf(a1);
                rowbuf[rb][lane] = a0;
                rowbuf[rb][64 + lane] = a1;
            } else {
                int c = lane;
                bool act2 = c < OUT;
                float a0 = 0.f;
                for (int e = st; e < en; ++e) {
                    int s = colsrc[e];
                    float t0 = lrelu(als[s * 2 + 0] + dv2.x);
                    float t1 = lrelu(als[s * 2 + 1] + dv2.y);
                    float w = (c < C) ? __expf(t0 - m0) * inv0 : __expf(t1 - m1) * inv1;
                    if (act2) a0 += w * bf2f(h[(size_t)s * OUT + c]);
                }
                if (act2) { out[(size_t)w2 * OUT + c] = f2bf(a0); rowbuf[rb][c] = a0; }
            }
        }
    }
    __syncthreads();
    // BN partial sums: reduce 8 rows in LDS, one atomicAdd pair per channel
    float* dst = &bnrep[(blockIdx.x & (NREP - 1)) * 2 * OUT];
    for (int c = threadIdx.x; c < OUT; c += 256) {
        float s = 0.f, ss = 0.f;
#pragma unroll
        for (int r = 0; r < 8; ++r) {
            float v = rowbuf[r][c];
            s += v; ss += v * v;
        }
        atomicAdd(&dst[c], s);
        atomicAdd(&dst[OUT + c], ss);
    }
}

// ---------------- Pooling (computes BN3 inline, applies +ReLU) + FC ----------------

__global__ void k_pool(const unsigned short* __restrict__ h, const int* __restrict__ batch,
                       const float* __restrict__ bnrep, const float* __restrict__ gamma,
                       const float* __restrict__ beta, float* __restrict__ pooled, int n) {
    const int K = 32;               // nodes per block
    int c = threadIdx.x;            // 0..127
    float s = 0.f, ss = 0.f;
#pragma unroll
    for (int r = 0; r < NREP; ++r) {
        s  += bnrep[r * 256 + c];
        ss += bnrep[r * 256 + 128 + c];
    }
    float mu = s / n;
    float var = ss / n - mu * mu;
    float scale = gamma[c] * rsqrtf(var + EPS);
    float shift = beta[c] - mu * scale;
    int n0 = blockIdx.x * K;
    if (n0 >= n) return;
    int nend = min(n, n0 + K);
    int curg = batch[n0];
    float m = 0.f;
    for (int nn = n0; nn < nend; ++nn) {
        int g = batch[nn];
        if (g != curg) {
            atomicMax((int*)&pooled[curg * 128 + c], __float_as_int(m));
            m = 0.f; curg = g;
        }
        float v = bf2f(h[(size_t)nn * 128 + c]) * scale + shift;
        m = fmaxf(m, v > 0.f ? v : 0.f);
    }
    atomicMax((int*)&pooled[curg * 128 + c], __float_as_int(m));
}

__global__ void k_fc(const float* __restrict__ pooled, const float* __restrict__ fcw,
                     const float* __restrict__ fcb, float* __restrict__ out) {
    int t = threadIdx.x;
    if (t >= NG * 10) return;
    int g = t / 10, j = t % 10;
    float acc = fcb[j];
#pragma unroll
    for (int c = 0; c < 128; ++c) acc += pooled[g * 128 + c] * fcw[c * 10 + j];
    out[g * 10 + j] = acc;
}

// ---------------- Host launch ----------------

extern "C" void kernel_launch(void* const* d_in, const int* in_sizes, int n_in,
                              void* d_out, int out_size, void* d_ws, size_t ws_size,
                              hipStream_t stream) {
    const float* x   = (const float*)d_in[0];
    const int*   ei  = (const int*)d_in[1];
    const int*   bat = (const int*)d_in[2];
    const float* W1  = (const float*)d_in[3];
    const float* as1 = (const float*)d_in[4];
    const float* ad1 = (const float*)d_in[5];
    // d_in[6] = b1 (cancels under BN)
    const float* g1  = (const float*)d_in[7];
    const float* be1 = (const float*)d_in[8];
    const float* W2  = (const float*)d_in[9];
    const float* as2 = (const float*)d_in[10];
    const float* ad2 = (const float*)d_in[11];
    const float* g2  = (const float*)d_in[13];
    const float* be2 = (const float*)d_in[14];
    const float* W3  = (const float*)d_in[15];
    const float* as3 = (const float*)d_in[16];
    const float* ad3 = (const float*)d_in[17];
    const float* g3  = (const float*)d_in[19];
    const float* be3 = (const float*)d_in[20];
    const float* fcw = (const float*)d_in[21];
    const float* fcb = (const float*)d_in[22];
    float* out = (float*)d_out;

    char* w = (char*)d_ws;
    size_t off = 0;
    auto take = [&](size_t bytes) {
        void* p = w + off;
        off += (bytes + 255) & ~(size_t)255;
        return p;
    };
    // ---- single zero-init region: bnrep1/2/3 | pooled ----
    constexpr size_t ZN = (size_t)NREP * 2 * (32 + 64 + 128) + NG * 128;
    char* zreg = (char*)take(ZN * 4);
    float* bnr1   = (float*)zreg;                    // NREP*64
    float* bnr2   = bnr1 + NREP * 64;                // NREP*128
    float* bnr3   = bnr2 + NREP * 128;               // NREP*256
    float* pooled = bnr3 + NREP * 256;               // NG*128

    int*   hist    = (int*)take((size_t)NBUCK * PHB * 4);
    int*   bsum    = (int*)take(NBUCK * 4);
    int*   bbase   = (int*)take((NBUCK + 1) * 4);
    int*   rowptr  = (int*)take((size_t)(NN + 1) * 4);
    int*   pairs   = (int*)take((size_t)TE * 4);
    int*   colsrc  = (int*)take((size_t)TE * 4);
    float* al_s    = (float*)take((size_t)NN * 2 * 4);
    float* al_d    = (float*)take((size_t)NN * 2 * 4);
    unsigned short* h0 = (unsigned short*)take((size_t)NN * 128 * 2);  // bf16
    unsigned short* h1 = (unsigned short*)take((size_t)NN * 128 * 2);  // bf16

    hipMemsetAsync(zreg, 0, ZN * 4, stream);

    // ---- CSR build (bucketed counting sort) ----
    k_hist<<<PHB, 256, 0, stream>>>(ei, hist);
    k_scanA<<<NBUCK, PHB, 0, stream>>>(hist, bsum);
    k_scanB<<<1, NBUCK, 0, stream>>>(bsum, bbase, rowptr);
    k_scatter<<<PHB, 256, 0, stream>>>(ei, hist, bbase, pairs);
    k_csr<<<NBUCK, 256, 0, stream>>>(pairs, bbase, rowptr, colsrc);

    const int AGG_BLOCKS = (NN + 7) / 8;   // 4 waves/block, 2 nodes/wave

    // ---- layer 1: 3 -> 32 (H=2, C=16) ----
    k_transform<3, 32, false, 1><<<(NN + 31) / 32, 256, 0, stream>>>(
        x, W1, as1, ad1, nullptr, nullptr, nullptr, h0, al_s, al_d, NN);
    k_aggregate<32><<<AGG_BLOCKS, 256, 0, stream>>>(rowptr, colsrc, h0, al_s, al_d, h1, bnr1);

    // ---- layer 2: 32 -> 64 (H=2, C=32) ----
    k_transform<32, 64, true, 4><<<(NN + 63) / 64, 256, 0, stream>>>(
        h1, W2, as2, ad2, bnr1, g1, be1, h0, al_s, al_d, NN);
    k_aggregate<64><<<AGG_BLOCKS, 256, 0, stream>>>(rowptr, colsrc, h0, al_s, al_d, h1, bnr2);

    // ---- layer 3: 64 -> 128 (H=2, C=64) ----
    k_transform<64, 128, true, 4><<<(NN + 31) / 32, 256, 0, stream>>>(
        h1, W3, as3, ad3, bnr2, g2, be2, h0, al_s, al_d, NN);
    k_aggregate<128><<<AGG_BLOCKS, 256, 0, stream>>>(rowptr, colsrc, h0, al_s, al_d, h1, bnr3);

    // ---- pool (BN3 inline) + fc ----
    k_pool<<<(NN + 31) / 32, 128, 0, stream>>>(h1, bat, bnr3, g3, be3, pooled, NN);
    k_fc<<<1, 640, 0, stream>>>(pooled, fcw, fcb, out);
}